// Round 11
// baseline (227.578 us; speedup 1.0000x reference)
//
#include <hip/hip_runtime.h>

// GCN N=100k, E=1.6M, H=64 — round-6 pipeline (best: 134.5us) + INSTRUMENTATION:
// the three idempotent bucket kernels are launched 3x each to expose their
// per-kernel cost via the total-duration delta:
//   dur ~= 134.5 + 2*(bdeg+bagg1+bagg2) + 6*gap
// (bdeg/bagg1/bagg2 recompute byte-identical outputs from unchanged inputs;
//  the P[256] flag atomicAdd only accumulates a value tested !=0 — harmless.)
//
// Hard-won rules (unchanged):
//   * scattered global stores/atomics ~60B memory-side each — scatter must be LDS.
//   * XCD-replicated accumulators don't help (device-scope atomics).
//   * cooperative grid.sync worse than dispatch boundaries.
//   * place micro-structure (stash/chunk/atomic-count) is NOT the bottleneck
//     (rounds 9,10 neutral).

#define HCH 64
#define CHUNK 4096
#define BSH 7
#define BSZ 128          // nodes per bucket
#define NBMAX 1024

__device__ __forceinline__ void lds_addf(float* p, float v) {
    __hip_atomic_fetch_add(p, v, __ATOMIC_RELAXED, __HIP_MEMORY_SCOPE_WORKGROUP);
}

__global__ __launch_bounds__(512) void k_place(const int* __restrict__ src,
                                               const int* __restrict__ dst, int e,
                                               int nb, int cap,
                                               int* __restrict__ cursor,
                                               int* __restrict__ ov_cursor,
                                               int* __restrict__ packed,
                                               int2* __restrict__ ovbuf) {
    __shared__ int h[NBMAX];
    __shared__ int basel[NBMAX];
    __shared__ int avail[NBMAX];
    __shared__ int lpv[CHUNK];
    __shared__ short lb[CHUNK];
    int t = threadIdx.x;
    for (int i = t; i < nb; i += 512) h[i] = 0;
    __syncthreads();
    int cbase = blockIdx.x * CHUNK;
    int rem = min(e - cbase, CHUNK);
#pragma unroll
    for (int g = 0; g < 2; g++) {
        int li = t * 8 + g * 4;
        if (li + 3 < rem) {
            int4 s4 = *(const int4*)(src + cbase + li);
            int4 d4 = *(const int4*)(dst + cbase + li);
#pragma unroll
            for (int q = 0; q < 4; q++) {
                int sv = (q == 0) ? s4.x : (q == 1) ? s4.y : (q == 2) ? s4.z : s4.w;
                int dv = (q == 0) ? d4.x : (q == 1) ? d4.y : (q == 2) ? d4.z : d4.w;
                int b = dv >> BSH;
                atomicAdd(&h[b], 1);
                lpv[li + q] = sv | ((dv & (BSZ - 1)) << 17);
                lb[li + q] = (short)b;
            }
        } else {
            for (int q = li; q < rem && q < li + 4; q++) {
                int sv = src[cbase + q], dv = dst[cbase + q];
                int b = dv >> BSH;
                atomicAdd(&h[b], 1);
                lpv[q] = sv | ((dv & (BSZ - 1)) << 17);
                lb[q] = (short)b;
            }
        }
    }
    __syncthreads();
    for (int i = t; i < nb; i += 512) {
        int my = h[i];
        int av = 0, base = 0;
        if (my) {
            base = atomicAdd(&cursor[i], my);   // bucket-relative cursor
            int room = cap - base;
            av = room < 0 ? 0 : (room > my ? my : room);
        }
        basel[i] = i * cap + base;
        avail[i] = av;
        h[i] = 0;  // reuse as local run cursor
    }
    __syncthreads();
    int lim = min(rem, t * 8 + 8);
    for (int li = t * 8; li < lim; li++) {
        int b = lb[li];
        int pv = lpv[li];
        int loc = atomicAdd(&h[b], 1);
        if (loc < avail[b]) {
            packed[basel[b] + loc] = pv;
        } else {
            int op = atomicAdd(ov_cursor, 1);
            ovbuf[op] = make_int2(pv & 0x1FFFF, (b << BSH) | (pv >> 17));
        }
    }
}

// per bucket: LDS histogram -> deg -> dinv, y. Block 0 threads 128..383 fold
// the P precompute (P+ P- B+ B- and |B| flag at P[256]).
__global__ __launch_bounds__(512) void k_bdeg(const int* __restrict__ packed,
                                              const int* __restrict__ cursor,
                                              const int* __restrict__ ov_cursor,
                                              const int2* __restrict__ ovbuf,
                                              int cap, const float* __restrict__ x, int n,
                                              float* __restrict__ dinv,
                                              float* __restrict__ y,
                                              const float* __restrict__ w1,
                                              const float* __restrict__ b1,
                                              const float* __restrict__ w2,
                                              float* __restrict__ P) {
    __shared__ int cnt[BSZ];
    int bk = blockIdx.x, t = threadIdx.x;
    int bbase = bk * cap;
    int bcnt = min(cursor[bk], cap);
    if (t < BSZ) cnt[t] = 0;
    __syncthreads();
    for (int base = 0; base < bcnt; base += 2048) {
        int i0 = base + t * 4;
        if (i0 + 3 < bcnt) {
            int4 p = *(const int4*)(packed + bbase + i0);
            atomicAdd(&cnt[p.x >> 17], 1);
            atomicAdd(&cnt[p.y >> 17], 1);
            atomicAdd(&cnt[p.z >> 17], 1);
            atomicAdd(&cnt[p.w >> 17], 1);
        } else {
            for (int i = i0; i < bcnt && i < i0 + 4; i++)
                atomicAdd(&cnt[packed[bbase + i] >> 17], 1);
        }
    }
    int ovc = *ov_cursor;
    for (int i = t; i < ovc; i += 512) {
        int2 o = ovbuf[i];
        if ((o.y >> BSH) == bk) atomicAdd(&cnt[o.y & (BSZ - 1)], 1);
    }
    __syncthreads();
    int node = (bk << BSH) + t;
    if (t < BSZ && node < n) {
        float dv = rsqrtf((float)(cnt[t] + 1));  // +1 self-loop
        dinv[node] = dv;
        y[node] = dv * x[node];
    }
    if (bk == 0 && t >= 128 && t < 384) {
        int tt = t - 128;
        int c = tt >> 6, j = tt & 63;
        float acc = 0.f;
        for (int k = 0; k < HCH; k++) {
            float w = w1[k], b = b1[k], v = w2[k * HCH + j];
            if (c == 0)      acc += (w > 0.f) ? w * v : 0.f;
            else if (c == 1) acc += (w < 0.f) ? w * v : 0.f;
            else if (c == 2) acc += (w > 0.f) ? b * v : (w == 0.f ? fmaxf(b, 0.f) * v : 0.f);
            else             acc += (w < 0.f) ? b * v : (w == 0.f ? fmaxf(b, 0.f) * v : 0.f);
        }
        P[c * HCH + j] = acc;
        if (c >= 2) {  // |B| flag -> P[256] (zeroed by host memset; 3x accumulate OK)
            float f = fabsf(acc);
#pragma unroll
            for (int off = 32; off; off >>= 1) f += __shfl_xor(f, off, 64);
            if ((t & 63) == 0) atomicAdd(&P[4 * HCH], f);
        }
    }
}

// per bucket: acc[localdst] += y[src] -> s -> val2 = (dinv*s, dinv)
__global__ __launch_bounds__(512) void k_bagg1(const int* __restrict__ packed,
                                               const int* __restrict__ cursor,
                                               const int* __restrict__ ov_cursor,
                                               const int2* __restrict__ ovbuf,
                                               int cap, const float* __restrict__ x,
                                               const float* __restrict__ dinv,
                                               const float* __restrict__ y, int n,
                                               float2* __restrict__ val2) {
    __shared__ float acc[BSZ];
    int bk = blockIdx.x, t = threadIdx.x;
    int bbase = bk * cap;
    int bcnt = min(cursor[bk], cap);
    if (t < BSZ) acc[t] = 0.f;
    __syncthreads();
    for (int base = 0; base < bcnt; base += 2048) {
        int i0 = base + t * 4;
        if (i0 + 3 < bcnt) {
            int4 p = *(const int4*)(packed + bbase + i0);
            float y0 = y[p.x & 0x1FFFF], y1 = y[p.y & 0x1FFFF];
            float y2 = y[p.z & 0x1FFFF], y3 = y[p.w & 0x1FFFF];
            lds_addf(&acc[p.x >> 17], y0);
            lds_addf(&acc[p.y >> 17], y1);
            lds_addf(&acc[p.z >> 17], y2);
            lds_addf(&acc[p.w >> 17], y3);
        } else {
            for (int i = i0; i < bcnt && i < i0 + 4; i++) {
                int p = packed[bbase + i];
                lds_addf(&acc[p >> 17], y[p & 0x1FFFF]);
            }
        }
    }
    int ovc = *ov_cursor;
    for (int i = t; i < ovc; i += 512) {
        int2 o = ovbuf[i];
        if ((o.y >> BSH) == bk) lds_addf(&acc[o.y & (BSZ - 1)], y[o.x]);
    }
    __syncthreads();
    int node = (bk << BSH) + t;
    if (t < BSZ && node < n) {
        float dv = dinv[node];
        float s = dv * (acc[t] + dv * x[node]);
        val2[node] = make_float2(dv * s, dv);
    }
}

// per bucket: sign-split LDS accumulate of val2[src] + fused epilogue -> out
__global__ __launch_bounds__(512) void k_bagg2(const int* __restrict__ packed,
                                               const int* __restrict__ cursor,
                                               const int* __restrict__ ov_cursor,
                                               const int2* __restrict__ ovbuf,
                                               int cap, const float2* __restrict__ val2,
                                               const float* __restrict__ dinv,
                                               const float* __restrict__ P,
                                               const float* __restrict__ b2,
                                               const float* __restrict__ wfc,
                                               const float* __restrict__ bfc,
                                               float* __restrict__ out, int n) {
    __shared__ float aa[2 * BSZ];   // [0..BSZ): positive, [BSZ..2BSZ): negative
    __shared__ float cc[2 * BSZ];
    __shared__ float sP[4 * HCH], sb2[HCH], swfc[HCH];
    int bk = blockIdx.x, t = threadIdx.x;
    int bbase = bk * cap;
    int bcnt = min(cursor[bk], cap);
    if (t < 2 * BSZ) { aa[t] = 0.f; cc[t] = 0.f; }
    if (t < 4 * HCH) sP[t] = P[t];
    if (t >= 256 && t < 320) sb2[t - 256] = b2[t - 256];
    if (t >= 320 && t < 384) swfc[t - 320] = wfc[t - 320];
    __syncthreads();
    bool useB = P[4 * HCH] != 0.f;
    for (int base = 0; base < bcnt; base += 2048) {
        int i0 = base + t * 4;
        if (i0 + 3 < bcnt) {
            int4 p = *(const int4*)(packed + bbase + i0);
            float2 v0 = val2[p.x & 0x1FFFF], v1 = val2[p.y & 0x1FFFF];
            float2 v2 = val2[p.z & 0x1FFFF], v3 = val2[p.w & 0x1FFFF];
            int o0 = (v0.x > 0.f ? 0 : BSZ) + (p.x >> 17);
            int o1 = (v1.x > 0.f ? 0 : BSZ) + (p.y >> 17);
            int o2 = (v2.x > 0.f ? 0 : BSZ) + (p.z >> 17);
            int o3 = (v3.x > 0.f ? 0 : BSZ) + (p.w >> 17);
            lds_addf(&aa[o0], v0.x); lds_addf(&aa[o1], v1.x);
            lds_addf(&aa[o2], v2.x); lds_addf(&aa[o3], v3.x);
            if (useB) {
                lds_addf(&cc[o0], v0.y); lds_addf(&cc[o1], v1.y);
                lds_addf(&cc[o2], v2.y); lds_addf(&cc[o3], v3.y);
            }
        } else {
            for (int i = i0; i < bcnt && i < i0 + 4; i++) {
                int p = packed[bbase + i];
                float2 v = val2[p & 0x1FFFF];
                int off = (v.x > 0.f ? 0 : BSZ) + (p >> 17);
                lds_addf(&aa[off], v.x);
                if (useB) lds_addf(&cc[off], v.y);
            }
        }
    }
    int ovc = *ov_cursor;
    for (int i = t; i < ovc; i += 512) {
        int2 o = ovbuf[i];
        if ((o.y >> BSH) == bk) {
            float2 v = val2[o.x];
            int off = (v.x > 0.f ? 0 : BSZ) + (o.y & (BSZ - 1));
            lds_addf(&aa[off], v.x);
            if (useB) lds_addf(&cc[off], v.y);
        }
    }
    __syncthreads();
    int node = (bk << BSH) + t;
    if (t >= BSZ || node >= n) return;
    float a_p = aa[t], a_m = aa[BSZ + t], c_p = cc[t], c_m = cc[BSZ + t];
    float2 sv = val2[node];  // self-loop
    if (sv.x > 0.f) { a_p += sv.x; c_p += sv.y; }
    else            { a_m += sv.x; c_m += sv.y; }
    float dv = dinv[node];
    float acc = 0.f;
#pragma unroll 8
    for (int j = 0; j < HCH; j++) {
        float z = dv * (a_p * sP[j] + a_m * sP[HCH + j] +
                        c_p * sP[2 * HCH + j] + c_m * sP[3 * HCH + j]) + sb2[j];
        z = fmaxf(z, 0.f);
        acc += z * swfc[j];
    }
    out[node] = acc + bfc[0];
}

extern "C" void kernel_launch(void* const* d_in, const int* in_sizes, int n_in,
                              void* d_out, int out_size, void* d_ws, size_t ws_size,
                              hipStream_t stream) {
    const float* x   = (const float*)d_in[0];
    const int*   ei  = (const int*)d_in[1];
    const float* w1  = (const float*)d_in[2];
    const float* b1  = (const float*)d_in[3];
    const float* w2  = (const float*)d_in[4];
    const float* b2  = (const float*)d_in[5];
    const float* wfc = (const float*)d_in[6];
    const float* bfc = (const float*)d_in[7];
    float* out = (float*)d_out;

    const int n = in_sizes[0];      // 100000
    const int e = in_sizes[1] / 2;  // 1600000
    const int* src = ei;
    const int* dst = ei + e;

    const int nb = (n + BSZ - 1) >> BSH;          // 782 buckets
    int avg = (e + nb - 1) / nb;                  // ~2047
    int cap = ((avg + avg / 4 + 64) + 15) & ~15;  // fixed bucket capacity

    auto al = [](size_t v) { return (v + 255) & ~(size_t)255; };
    char* ws = (char*)d_ws;
    size_t o = 0;
    int* cursor    = (int*)(ws + o);  o += (size_t)NBMAX * 4;
    int* ov_cursor = (int*)(ws + o);  o += 256;
    float* P       = (float*)(ws + o); o += (4 * HCH + 8) * 4;
    size_t zbytes = o;                 // single memset: cursors + ov + P/flag
    o = al(o);
    float* dinv  = (float*)(ws + o);  o = al(o + (size_t)n * 4);
    float* y     = (float*)(ws + o);  o = al(o + (size_t)n * 4);
    float2* val2 = (float2*)(ws + o); o = al(o + (size_t)n * 8);
    int* packed  = (int*)(ws + o);    o = al(o + (size_t)nb * cap * 4);
    int2* ovbuf  = (int2*)(ws + o);   o = al(o + (size_t)e * 8);
    (void)ws_size;

    const int nchunk = (e + CHUNK - 1) / CHUNK;  // 391 chunks

    hipMemsetAsync(ws, 0, zbytes, stream);
    k_place<<<nchunk, 512, 0, stream>>>(src, dst, e, nb, cap, cursor, ov_cursor,
                                        packed, ovbuf);
    // INSTRUMENTATION: 3x each (idempotent) — dur delta = 2*(bdeg+bagg1+bagg2)+6*gap
    for (int r = 0; r < 3; r++)
        k_bdeg<<<nb, 512, 0, stream>>>(packed, cursor, ov_cursor, ovbuf, cap, x, n,
                                       dinv, y, w1, b1, w2, P);
    for (int r = 0; r < 3; r++)
        k_bagg1<<<nb, 512, 0, stream>>>(packed, cursor, ov_cursor, ovbuf, cap, x, dinv, y,
                                        n, val2);
    for (int r = 0; r < 3; r++)
        k_bagg2<<<nb, 512, 0, stream>>>(packed, cursor, ov_cursor, ovbuf, cap, val2, dinv,
                                        P, b2, wfc, bfc, out, n);
}